// Round 16
// baseline (142.996 us; speedup 1.0000x reference)
//
#include <hip/hip_runtime.h>
#include <hip/hip_bf16.h>
#include <math.h>

#define P_N   2048
#define B_N   10000
#define NB    15
#define MROWS (P_N * NB)   // 30720

typedef __bf16 bf16x8 __attribute__((ext_vector_type(8)));
typedef float  f32x4  __attribute__((ext_vector_type(4)));

__device__ __forceinline__ float bf2f(unsigned short u) {
    union { unsigned int i; float f; } v; v.i = ((unsigned int)u) << 16; return v.f;
}
__device__ __forceinline__ unsigned short f2bf(float f) {
    union { float f; unsigned int i; } v; v.f = f;
    unsigned int i = v.i;
    i += 0x7FFFu + ((i >> 16) & 1u);
    return (unsigned short)(i >> 16);
}
__device__ __forceinline__ void gld_lds16(const unsigned short* g, unsigned short* l) {
    __builtin_amdgcn_global_load_lds(
        (const __attribute__((address_space(1))) unsigned int*)g,
        (__attribute__((address_space(3))) unsigned int*)l, 16, 0, 0);
}
// monotone u32 key for f32 (x<y iff key(x)<key(y)); all real keys > 0
__device__ __forceinline__ unsigned fkey(float f) {
    unsigned b = __float_as_uint(f);
    return (b & 0x80000000u) ? ~b : (b | 0x80000000u);
}
__device__ __forceinline__ float funkey(unsigned key) {
    unsigned b = (key & 0x80000000u) ? (key ^ 0x80000000u) : ~key;
    return __uint_as_float(b);
}

// ---- K0 (fused front): W1/W2 transpose; zero stats+mkey; V/c; h->bf16 ------
// block ranges: [0,144) transpose | [144,2196) zero | [2196,2198) V/c |
//               [2198,2326) hbf
__global__ __launch_bounds__(256) void k_front(const float* __restrict__ W1,
        const float* __restrict__ W2, unsigned short* __restrict__ w1t,
        unsigned short* __restrict__ w2t, float* __restrict__ stats,
        const float* __restrict__ h, unsigned short* __restrict__ hbf,
        const float* __restrict__ Wsp, const float* __restrict__ bsp,
        const float* __restrict__ b1, float* __restrict__ V0,
        float* __restrict__ V1, float* __restrict__ cvec) {
    __shared__ unsigned short t[64][65];
    int blk = blockIdx.x, tid = threadIdx.x;
    if (blk < 144) {                          // -------- weight transpose
        const float* W; unsigned short* O; int NC, K, tr, tc;
        if (blk < 16) { W = W1; O = w1t; NC = 512; K = 128; tr = blk & 1; tc = blk >> 1; }
        else { int b = blk - 16; W = W2; O = w2t; NC = 1024; K = 512; tr = b & 7; tc = b >> 3; }
        int r0 = tr * 64, c0 = tc * 64;
        int cx = tid & 63, rg = tid >> 6;
#pragma unroll
        for (int i = 0; i < 16; ++i) {
            int r = rg * 16 + i;
            t[r][cx] = f2bf(W[(size_t)(r0 + r) * NC + c0 + cx]);
        }
        __syncthreads();
#pragma unroll
        for (int i = 0; i < 16; ++i) {
            int n = rg * 16 + i;
            O[(size_t)(c0 + n) * K + r0 + cx] = t[cx][n];
        }
    } else if (blk < 2196) {                  // -------- zero stats+mkey (contig)
        int zidx = (blk - 144) * 256 + tid;
        if (zidx < 525056) {                  // (12288 + 8388608) / 16
            uint4 z = {0u, 0u, 0u, 0u};
            ((uint4*)stats)[zidx] = z;
        }
    } else if (blk < 2198) {                  // -------- V = Wsp@W1_top, c
        int col = (blk - 2196) * 256 + tid;   // 0..511
        float v0 = 0.f, v1 = 0.f, cc = 0.f;
        for (int e = 0; e < 64; ++e) {
            float w = W1[(size_t)e * 512 + col];
            v0 = fmaf(Wsp[e], w, v0);
            v1 = fmaf(Wsp[64 + e], w, v1);
            cc = fmaf(bsp[e], w, cc);
        }
        V0[col] = v0; V1[col] = v1; cvec[col] = cc + b1[col];
    } else {                                  // -------- h -> bf16 (2048x64)
        int base = (blk - 2198) * 1024 + tid * 4;
        float4 hv = *(const float4*)(h + base);
        unsigned short ub[4] = {f2bf(hv.x), f2bf(hv.y), f2bf(hv.z), f2bf(hv.w)};
        *(uint2*)(hbf + base) = *(uint2*)ub;
    }
}

// ---- K1: build 40x40 spatial grid over boundary points (cell = 2.0) --------
__global__ __launch_bounds__(1024) void k_build(const float* __restrict__ bpts,
        int* __restrict__ cellstart, float2* __restrict__ sxy, int* __restrict__ sidx) {
    __shared__ unsigned int cnt[1600];
    __shared__ unsigned int offs[1600];
    int tid = threadIdx.x;
    for (int i = tid; i < 1600; i += 1024) cnt[i] = 0u;
    __syncthreads();
    const float2* bp2 = (const float2*)bpts;
    for (int i = tid; i < B_N; i += 1024) {
        float2 pt = bp2[i];
        int cxp = min(39, max(0, (int)floorf((pt.x + 40.0f) * 0.5f)));
        int cyp = min(39, max(0, (int)floorf((pt.y + 40.0f) * 0.5f)));
        atomicAdd(&cnt[cyp * 40 + cxp], 1u);
    }
    __syncthreads();
    // inclusive Hillis-Steele scan over 1600 (each thread owns <=2 slots)
    for (int off = 1; off < 1600; off <<= 1) {
        unsigned v0 = 0u, v1 = 0u;
        int i0 = tid, i1 = tid + 1024;
        if (i0 < 1600) v0 = cnt[i0] + ((i0 >= off) ? cnt[i0 - off] : 0u);
        if (i1 < 1600) v1 = cnt[i1] + ((i1 >= off) ? cnt[i1 - off] : 0u);
        __syncthreads();
        if (i0 < 1600) cnt[i0] = v0;
        if (i1 < 1600) cnt[i1] = v1;
        __syncthreads();
    }
    for (int i = tid; i < 1600; i += 1024) {
        offs[i] = (i == 0) ? 0u : cnt[i - 1];
        cellstart[i + 1] = (int)cnt[i];
    }
    if (tid == 0) cellstart[0] = 0;
    __syncthreads();
    for (int i = tid; i < B_N; i += 1024) {
        float2 pt = bp2[i];
        int cxp = min(39, max(0, (int)floorf((pt.x + 40.0f) * 0.5f)));
        int cyp = min(39, max(0, (int)floorf((pt.y + 40.0f) * 0.5f)));
        unsigned pos = atomicAdd(&offs[cyp * 40 + cxp], 1u);
        sxy[pos] = pt;
        sidx[pos] = i;
    }
}

// ---- K2: per-ped pruned scan (3x3 cells, r2<=4 only) + rel output -----------
// Exact vs full scan: fallback (r=2.0, appended AFTER points) beats any point
// with r>2.0; tie at r==2.0 goes to the point (smaller flat index). So only
// points with r2<=4.0 can ever be chosen; empty -> key=~0 -> NaN -> fallback.
__global__ __launch_bounds__(256) void k_pscan(
        const float* __restrict__ end_pos, const float* __restrict__ rel_pos,
        const float* __restrict__ bpts, const float2* __restrict__ sxy,
        const int* __restrict__ sidx, const int* __restrict__ cellstart,
        float* __restrict__ rel) {
    __shared__ unsigned long long skey[4][16];
    int tid = threadIdx.x, wave = tid >> 6, lane = tid & 63;
    int p = blockIdx.x * 4 + wave;
    if (lane < NB) skey[wave][lane] = ~0ull;
    __syncthreads();

    float ex = end_pos[2 * p], ey = end_pos[2 * p + 1];
    float rx = rel_pos[2 * p], ry = rel_pos[2 * p + 1];
    float rr = rx * rx + ry * ry;
    float c, s;
    if (rr > 0.0f) { float inv = 1.0f / sqrtf(rr); c = rx * inv; s = ry * inv; }
    else           { c = 1.0f; s = 0.0f; }

    const float T0 = -4.704630109f, T1 = -2.246036774f, T2 = -1.376381920f,
                T3 = -0.900404044f, T4 = -0.577350269f, T5 = -0.324919696f,
                T6 = -0.105104235f, T7 =  0.105104235f, T8 =  0.324919696f,
                T9 =  0.577350269f, T10 = 0.900404044f, T11 = 1.376381920f,
                T12 = 2.246036774f, T13 = 4.704630109f;

    int cx = min(38, max(1, (int)floorf((ex + 40.0f) * 0.5f)));
    int cy = min(38, max(1, (int)floorf((ey + 40.0f) * 0.5f)));
#pragma unroll
    for (int oy = -1; oy <= 1; ++oy) {
        int rowc = (cy + oy) * 40 + cx;
        int st = cellstart[rowc - 1];
        int en = cellstart[rowc + 2];        // 3 consecutive cells = one range
        for (int i = st + lane; i < en; i += 64) {
            float2 pt = sxy[i];
            float dx = pt.x - ex, dy = pt.y - ey;
            float xb = dx * c + dy * s;
            float yb = dy * c - dx * s;
            float r2 = xb * xb + yb * yb;
            if (xb > 0.0f && r2 <= 4.0f) {
                bool v3 = yb > T7 * xb;
                float ta = v3 ? T11 : T3;
                bool v2 = yb > ta * xb;
                float tb = v3 ? (v2 ? T13 : T9) : (v2 ? T5 : T1);
                bool v1 = yb > tb * xb;
                float tc = v3 ? (v2 ? (v1 ? 3.0e38f : T12) : (v1 ? T10 : T8))
                              : (v2 ? (v1 ? T6 : T4)       : (v1 ? T2 : T0));
                bool v0 = yb > tc * xb;
                int bin = (v3 ? 8 : 0) + (v2 ? 4 : 0) + (v1 ? 2 : 0) + (v0 ? 1 : 0);
                unsigned long long key =
                    ((unsigned long long)__float_as_uint(r2) << 32) | (unsigned)sidx[i];
                atomicMin(&skey[wave][bin], key);
            }
        }
    }
    __syncthreads();
    if (lane < NB) {
        unsigned long long key = skey[wave][lane];
        float r = sqrtf(__uint_as_float((unsigned int)(key >> 32)));
        float relx, rely;
        if (r <= 2.0f) {                      // NaN-safe: empty bin -> fallback
            int b = (int)(key & 0xFFFFFFFFu);
            relx = bpts[2 * b] - ex; rely = bpts[2 * b + 1] - ey;
        } else {
            float th = ((float)lane + 0.5f) * (float)(M_PI / 15.0) - (float)(M_PI / 2.0);
            float xc = 2.0f * cosf(th), yc = 2.0f * sinf(th);
            relx = xc * c - yc * s;
            rely = xc * s + yc * c;
        }
        rel[(size_t)(p * NB + lane) * 2]     = relx;
        rel[(size_t)(p * NB + lane) * 2 + 1] = rely;
    }
}

// ---- K3: H' = hbf @ W1_bot^T  (2048 x 512, K=64), f32 out -------------------
__global__ __launch_bounds__(512) void k_hgemm(const unsigned short* __restrict__ hbf,
        const unsigned short* __restrict__ w1t, float* __restrict__ Hp) {
    __shared__ __align__(16) unsigned short lds[24576];  // 2 subtiles x (A 4096|B 8192)
    int tid = threadIdx.x;
    int bm = blockIdx.x & 15, bnn = blockIdx.x >> 4;     // 16 x 2 blocks
    int row0 = bm << 7, col0 = bnn << 8;
    int lane = tid & 63, wave = tid >> 6;
    int wr = wave >> 2, wc = wave & 3;                   // wave out: 64r x 64c
    int frow = lane & 15, kq = lane >> 4;

    f32x4 zero = {0.f, 0.f, 0.f, 0.f};
    f32x4 acc[4][4];
#pragma unroll
    for (int i = 0; i < 4; ++i)
#pragma unroll
        for (int j = 0; j < 4; ++j) acc[i][j] = zero;

    // 48 chunks (16r x 32k, [kq][frow][8]); wave w stages ch = w*6+k
#pragma unroll
    for (int k = 0; k < 6; ++k) {
        int ch = wave * 6 + k;
        int s = (ch >= 24) ? 1 : 0;
        int r = ch - s * 24;
        unsigned short* dst = lds + s * 12288 + r * 512;
        const unsigned short* src =
            (r < 8) ? (hbf + (size_t)(row0 + r * 16 + frow) * 64 + s * 32 + kq * 8)
                    : (w1t + (size_t)(col0 + (r - 8) * 16 + frow) * 128 + 64 + s * 32 + kq * 8);
        gld_lds16(src, dst);
    }
    asm volatile("s_waitcnt vmcnt(0)" ::: "memory");
    __builtin_amdgcn_s_barrier();
    asm volatile("" ::: "memory");

#pragma unroll
    for (int s = 0; s < 2; ++s) {
        const unsigned short* sub = lds + s * 12288;
        bf16x8 af[4], bfv[4];
#pragma unroll
        for (int i = 0; i < 4; ++i)
            af[i] = *(const bf16x8*)&sub[(wr * 4 + i) * 512 + kq * 128 + frow * 8];
#pragma unroll
        for (int j = 0; j < 4; ++j)
            bfv[j] = *(const bf16x8*)&sub[4096 + (wc * 4 + j) * 512 + kq * 128 + frow * 8];
#pragma unroll
        for (int i = 0; i < 4; ++i)
#pragma unroll
            for (int j = 0; j < 4; ++j)
                acc[i][j] = __builtin_amdgcn_mfma_f32_16x16x32_bf16(af[i], bfv[j], acc[i][j], 0, 0, 0);
    }

#pragma unroll
    for (int i = 0; i < 4; ++i)
#pragma unroll
        for (int j = 0; j < 4; ++j)
#pragma unroll
            for (int r = 0; r < 4; ++r) {
                int row = row0 + wr * 64 + i * 16 + kq * 4 + r;
                int col = col0 + wc * 64 + j * 16 + frow;
                Hp[(size_t)row * 512 + col] = acc[i][j][r];
            }
}

// ---- K4: BN1 stats by on-the-fly recompute: y = relx*V0 + rely*V1 + (c+H') --
__global__ __launch_bounds__(256) void k_stat1(const float* __restrict__ Hp,
        const float* __restrict__ rel, const float* __restrict__ V0,
        const float* __restrict__ V1, const float* __restrict__ cvec,
        float* __restrict__ s1, float* __restrict__ q1) {
    __shared__ float s_s[512], s_q[512];
    int tid = threadIdx.x;
    int pi = tid >> 6, seg = tid & 63;
    int p = blockIdx.x * 4 + pi;
    s_s[tid] = 0.f; s_s[tid + 256] = 0.f;
    s_q[tid] = 0.f; s_q[tid + 256] = 0.f;
    __syncthreads();

    float4 ha = *(const float4*)(Hp + (size_t)p * 512 + seg * 8);
    float4 hb = *(const float4*)(Hp + (size_t)p * 512 + seg * 8 + 4);
    float4 ca = *(const float4*)(cvec + seg * 8);
    float4 cb = *(const float4*)(cvec + seg * 8 + 4);
    float4 va = *(const float4*)(V0 + seg * 8), vb = *(const float4*)(V0 + seg * 8 + 4);
    float4 wa = *(const float4*)(V1 + seg * 8), wb = *(const float4*)(V1 + seg * 8 + 4);
    float hc[8] = {ha.x+ca.x, ha.y+ca.y, ha.z+ca.z, ha.w+ca.w,
                   hb.x+cb.x, hb.y+cb.y, hb.z+cb.z, hb.w+cb.w};
    float v0[8] = {va.x,va.y,va.z,va.w,vb.x,vb.y,vb.z,vb.w};
    float v1[8] = {wa.x,wa.y,wa.z,wa.w,wb.x,wb.y,wb.z,wb.w};
    float ss[8] = {0,0,0,0,0,0,0,0}, qq[8] = {0,0,0,0,0,0,0,0};
#pragma unroll
    for (int cell = 0; cell < NB; ++cell) {
        float2 rl = *(const float2*)(rel + (size_t)(p * NB + cell) * 2);
#pragma unroll
        for (int j = 0; j < 8; ++j) {
            float y = fmaf(rl.x, v0[j], fmaf(rl.y, v1[j], hc[j]));
            ss[j] += y; qq[j] = fmaf(y, y, qq[j]);
        }
    }
#pragma unroll
    for (int j = 0; j < 8; ++j) {
        atomicAdd(&s_s[seg * 8 + j], ss[j]);
        atomicAdd(&s_q[seg * 8 + j], qq[j]);
    }
    __syncthreads();
    atomicAdd(&s1[tid], s_s[tid]);
    atomicAdd(&s1[tid + 256], s_s[tid + 256]);
    atomicAdd(&q1[tid], s_q[tid]);
    atomicAdd(&q1[tid + 256], s_q[tid + 256]);
}

// ---- K5: write Y1 = relu(sc*y + sh) as bf16 (inline BN1 coefficients) -------
__global__ __launch_bounds__(256) void k_y1w(const float* __restrict__ Hp,
        const float* __restrict__ rel, const float* __restrict__ V0,
        const float* __restrict__ V1, const float* __restrict__ cvec,
        const float* __restrict__ s1, const float* __restrict__ q1,
        const float* __restrict__ g1, const float* __restrict__ be1,
        unsigned short* __restrict__ Y1) {
    int tid = threadIdx.x;
    int p = blockIdx.x;
    int seg = tid & 63, cg = tid >> 6;
    const float invN = 1.0f / (float)MROWS;
    float4 ha = *(const float4*)(Hp + (size_t)p * 512 + seg * 8);
    float4 hb = *(const float4*)(Hp + (size_t)p * 512 + seg * 8 + 4);
    float4 ca = *(const float4*)(cvec + seg * 8);
    float4 cb = *(const float4*)(cvec + seg * 8 + 4);
    float4 va = *(const float4*)(V0 + seg * 8), vb = *(const float4*)(V0 + seg * 8 + 4);
    float4 wa = *(const float4*)(V1 + seg * 8), wb = *(const float4*)(V1 + seg * 8 + 4);
    float hc[8] = {ha.x+ca.x, ha.y+ca.y, ha.z+ca.z, ha.w+ca.w,
                   hb.x+cb.x, hb.y+cb.y, hb.z+cb.z, hb.w+cb.w};
    float v0[8] = {va.x,va.y,va.z,va.w,vb.x,vb.y,vb.z,vb.w};
    float v1[8] = {wa.x,wa.y,wa.z,wa.w,wb.x,wb.y,wb.z,wb.w};
    float sc[8], sh[8];
#pragma unroll
    for (int j = 0; j < 8; ++j) {
        int cc = seg * 8 + j;
        float m = s1[cc] * invN;
        float v = q1[cc] * invN - m * m;
        float k = g1[cc] * rsqrtf(v + 1e-5f);
        sc[j] = k; sh[j] = be1[cc] - m * k;
    }
#pragma unroll
    for (int i = 0; i < 4; ++i) {
        int cell = cg + i * 4;
        if (cell < NB) {
            float2 rl = *(const float2*)(rel + (size_t)(p * NB + cell) * 2);
            unsigned short ub[8];
#pragma unroll
            for (int j = 0; j < 8; ++j) {
                float y = fmaf(rl.x, v0[j], fmaf(rl.y, v1[j], hc[j]));
                float z = fmaxf(fmaf(y, sc[j], sh[j]), 0.0f);
                ub[j] = f2bf(z);
            }
            *(uint4*)(Y1 + (size_t)(p * NB + cell) * 512 + seg * 8) = *(uint4*)ub;
        }
    }
}

// ---- GEMM2: 256x256, BK=64, subtile-phase pipeline (R13-verified, ~60 us) ---
template<int K, bool WRITE_C>
__global__ __launch_bounds__(512) void k_gemm256(
        const unsigned short* __restrict__ A, const unsigned short* __restrict__ Bt,
        const float* __restrict__ bias, unsigned short* __restrict__ C,
        int N, float* __restrict__ osum, float* __restrict__ osq,
        unsigned int* __restrict__ mkey) {
    __shared__ __align__(16) unsigned short lds[65536];  // 2 bufs x 32768 elems
    int tid = threadIdx.x;

    int nbt = N >> 8;
    int d = blockIdx.x;
    int m5 = d >> 3;
    int bn = m5 % nbt;
    int bm = (d & 7) + ((m5 / nbt) << 3);
    int row0 = bm << 8, col0 = bn << 8;

    int lane = tid & 63, wave = tid >> 6;
    int wr = wave >> 2, wc = wave & 3;
    int frow = lane & 15, kq = lane >> 4;

    f32x4 zero = {0.f, 0.f, 0.f, 0.f};
    f32x4 acc[8][4];
#pragma unroll
    for (int i = 0; i < 8; ++i)
#pragma unroll
        for (int j = 0; j < 4; ++j) acc[i][j] = zero;

    const unsigned short* gsrc =
        (wave < 4) ? (A  + (size_t)(row0 + (wave << 6) + frow) * K + kq * 8)
                   : (Bt + (size_t)(col0 + ((wave - 4) << 6) + frow) * K + kq * 8);
    unsigned regbase = (wave < 4) ? (unsigned)wave * 2048
                                  : 8192u + (unsigned)(wave - 4) * 2048;

    auto issue2 = [&](int t, int s, int hp) {
        unsigned short* dst = lds + (t & 1) * 32768 + s * 16384 + regbase + hp * 1024;
        const unsigned short* src = gsrc + t * 64 + s * 32 + (size_t)(hp * 32) * K;
        gld_lds16(src,                  dst);
        gld_lds16(src + (size_t)16 * K, dst + 512);
    };

    constexpr int NT = K / 64;
    static_assert(NT >= 2, "need >=2 K-tiles");

    issue2(0, 0, 0); issue2(0, 0, 1); issue2(0, 1, 0); issue2(0, 1, 1);

#pragma unroll
    for (int t = 0; t < NT; ++t) {
        const unsigned short* buf = lds + (t & 1) * 32768;
        bool more = (t + 1 < NT);
#pragma unroll
        for (int s = 0; s < 2; ++s) {
            const unsigned short* sub = buf + s * 16384;
            if (more || s == 0) asm volatile("s_waitcnt vmcnt(4)" ::: "memory");
            else                asm volatile("s_waitcnt vmcnt(0)" ::: "memory");
            __builtin_amdgcn_s_barrier();
            asm volatile("" ::: "memory");
            bf16x8 bfv[4], af[4];
#pragma unroll
            for (int j = 0; j < 4; ++j)
                bfv[j] = *(const bf16x8*)&sub[8192 + (wc * 4 + j) * 512 + kq * 128 + frow * 8];
#pragma unroll
            for (int i = 0; i < 4; ++i)
                af[i] = *(const bf16x8*)&sub[(wr * 8 + i) * 512 + kq * 128 + frow * 8];
            if (more) issue2(t + 1, s, 0);
            __builtin_amdgcn_s_barrier();
            asm volatile("" ::: "memory");
            __builtin_amdgcn_s_setprio(1);
#pragma unroll
            for (int i = 0; i < 4; ++i)
#pragma unroll
                for (int j = 0; j < 4; ++j)
                    acc[i][j] = __builtin_amdgcn_mfma_f32_16x16x32_bf16(af[i], bfv[j], acc[i][j], 0, 0, 0);
            __builtin_amdgcn_s_setprio(0);
#pragma unroll
            for (int i = 0; i < 4; ++i)
                af[i] = *(const bf16x8*)&sub[(wr * 8 + 4 + i) * 512 + kq * 128 + frow * 8];
            if (more) issue2(t + 1, s, 1);
            __builtin_amdgcn_s_barrier();
            asm volatile("" ::: "memory");
            __builtin_amdgcn_s_setprio(1);
#pragma unroll
            for (int i = 0; i < 4; ++i)
#pragma unroll
                for (int j = 0; j < 4; ++j)
                    acc[4 + i][j] = __builtin_amdgcn_mfma_f32_16x16x32_bf16(af[i], bfv[j], acc[4 + i][j], 0, 0, 0);
            __builtin_amdgcn_s_setprio(0);
        }
    }

    float bv[4];
#pragma unroll
    for (int j = 0; j < 4; ++j) bv[j] = bias[col0 + wc * 64 + j * 16 + frow];

#pragma unroll
    for (int j = 0; j < 4; ++j) {
        int col = col0 + wc * 64 + j * 16 + frow;
        float csum = 0.f, csq = 0.f;
#pragma unroll
        for (int i = 0; i < 8; ++i) {
#pragma unroll
            for (int r = 0; r < 4; ++r) {
                float y = acc[i][j][r] + bv[j];
                csum += y; csq = fmaf(y, y, csq);
            }
        }
        csum += __shfl_xor(csum, 16); csum += __shfl_xor(csum, 32);
        csq  += __shfl_xor(csq, 16);  csq  += __shfl_xor(csq, 32);
        if (lane < 16) { atomicAdd(&osum[col], csum); atomicAdd(&osq[col], csq); }
    }

    unsigned short* ldsC = lds;
#pragma unroll
    for (int b = 0; b < 4; ++b) {
        __syncthreads();
        if (wr == (b >> 1)) {
#pragma unroll
            for (int j = 0; j < 4; ++j) {
#pragma unroll
                for (int ii = 0; ii < 4; ++ii) {
                    int i = (b & 1) * 4 + ii;
#pragma unroll
                    for (int r = 0; r < 4; ++r) {
                        float y = acc[i][j][r] + bv[j];
                        ldsC[(ii * 16 + kq * 4 + r) * 264 + wc * 64 + j * 16 + frow] = f2bf(y);
                    }
                }
            }
        }
        __syncthreads();
        if (WRITE_C) {
#pragma unroll
            for (int it = 0; it < 4; ++it) {
                int s = it * 512 + tid;
                int brow = s >> 5, seg = s & 31;
                *(uint4*)(C + (size_t)(row0 + b * 64 + brow) * N + col0 + seg * 8) =
                    *(const uint4*)&ldsC[brow * 264 + seg * 8];
            }
        } else {
            int col = tid & 255, half = tid >> 8;
            int lrow0 = half * 32;
            int grow = row0 + b * 64 + lrow0;
            int curp = grow / 15;
            int rem = 15 - (grow - curp * 15);
            float mx = -3.0e38f;
#pragma unroll
            for (int r = 0; r < 32; ++r) {
                mx = fmaxf(mx, bf2f(ldsC[(lrow0 + r) * 264 + col]));
                if (--rem == 0) {
                    atomicMax(&mkey[(size_t)curp * 1024 + col0 + col], fkey(mx));
                    mx = -3.0e38f; ++curp; rem = 15;
                }
            }
            if (rem != 15)
                atomicMax(&mkey[(size_t)curp * 1024 + col0 + col], fkey(mx));
        }
    }
}

// ---- finalize: out = relu(sc2 * max_y + sh2) from u32-keyed maxima ----------
__global__ void k_bnfin(const unsigned int* __restrict__ mkey, const float* __restrict__ s2,
                        const float* __restrict__ q2, const float* __restrict__ g2,
                        const float* __restrict__ be2, float* __restrict__ out) {
    int idx = blockIdx.x * 256 + threadIdx.x;
    int p = idx >> 7, cb = idx & 127;
    int c0 = cb << 3;
    const float invN = 1.0f / (float)MROWS;
    float4 sa = *(const float4*)(s2 + c0),  sb = *(const float4*)(s2 + c0 + 4);
    float4 qa = *(const float4*)(q2 + c0),  qb = *(const float4*)(q2 + c0 + 4);
    float4 ga = *(const float4*)(g2 + c0),  gb = *(const float4*)(g2 + c0 + 4);
    float4 ea = *(const float4*)(be2 + c0), eb = *(const float4*)(be2 + c0 + 4);
    float sv[8] = {sa.x,sa.y,sa.z,sa.w,sb.x,sb.y,sb.z,sb.w};
    float qv[8] = {qa.x,qa.y,qa.z,qa.w,qb.x,qb.y,qb.z,qb.w};
    float gv[8] = {ga.x,ga.y,ga.z,ga.w,gb.x,gb.y,gb.z,gb.w};
    float ev[8] = {ea.x,ea.y,ea.z,ea.w,eb.x,eb.y,eb.z,eb.w};
    uint4 k0 = *(const uint4*)(mkey + (size_t)p * 1024 + c0);
    uint4 k1 = *(const uint4*)(mkey + (size_t)p * 1024 + c0 + 4);
    unsigned kv[8] = {k0.x,k0.y,k0.z,k0.w,k1.x,k1.y,k1.z,k1.w};
    float o[8];
#pragma unroll
    for (int j = 0; j < 8; ++j) {
        float m = sv[j] * invN;
        float v = qv[j] * invN - m * m;
        float k = gv[j] * rsqrtf(v + 1e-5f);
        float sh = ev[j] - m * k;
        o[j] = fmaxf(fmaf(funkey(kv[j]), k, sh), 0.0f);
    }
    float4 o0 = {o[0], o[1], o[2], o[3]};
    float4 o1 = {o[4], o[5], o[6], o[7]};
    *(float4*)(out + (size_t)p * 1024 + c0)     = o0;
    *(float4*)(out + (size_t)p * 1024 + c0 + 4) = o1;
}

extern "C" void kernel_launch(void* const* d_in, const int* in_sizes, int n_in,
                              void* d_out, int out_size, void* d_ws, size_t ws_size,
                              hipStream_t stream) {
    const float* h       = (const float*)d_in[0];
    const float* end_pos = (const float*)d_in[1];
    const float* rel_pos = (const float*)d_in[2];
    const float* bpts    = (const float*)d_in[3];
    const float* Wsp     = (const float*)d_in[4];
    const float* bsp     = (const float*)d_in[5];
    const float* W1      = (const float*)d_in[6];
    const float* b1      = (const float*)d_in[7];
    const float* g1      = (const float*)d_in[8];
    const float* be1     = (const float*)d_in[9];
    const float* W2      = (const float*)d_in[10];
    const float* b2      = (const float*)d_in[11];
    const float* g2      = (const float*)d_in[12];
    const float* be2     = (const float*)d_in[13];
    float* out = (float*)d_out;

    // ws: [stats 12288][mkey 8388608][grid: cellstart/sxy/sidx][w1t][w2t]
    //     [hbf][V0/V1/c][Hp][rel][Y1]
    char* ws = (char*)d_ws;
    float* s1  = (float*)ws;
    float* q1  = s1 + 512;
    float* s2  = q1 + 512;
    float* q2  = s2 + 1024;
    unsigned int* mkey = (unsigned int*)(ws + 12288);
    int*    cellstart  = (int*)(ws + 8400896);           // 1601 x 4 -> 6416
    float2* sxy        = (float2*)(ws + 8407312);        // 10000 x 8 = 80000
    int*    sidx       = (int*)(ws + 8487312);           // 10000 x 4 = 40000
    unsigned short* w1t = (unsigned short*)(ws + 9629696);
    unsigned short* w2t = (unsigned short*)(ws + 9760768);
    unsigned short* hbf = (unsigned short*)(ws + 10809344);
    float* V0   = (float*)(ws + 11071488);
    float* V1   = V0 + 512;
    float* cvec = V1 + 512;
    float* Hp   = (float*)(ws + 11081728);
    float* rel  = (float*)(ws + 15276032);
    unsigned short* Y1 = (unsigned short*)(ws + 15521792);

    k_front<<<2326, 256, 0, stream>>>(W1, W2, w1t, w2t, s1, h, hbf,
                                      Wsp, bsp, b1, V0, V1, cvec);
    k_build<<<1, 1024, 0, stream>>>(bpts, cellstart, sxy, sidx);
    k_pscan<<<P_N / 4, 256, 0, stream>>>(end_pos, rel_pos, bpts, sxy, sidx,
                                         cellstart, rel);
    k_hgemm<<<32, 512, 0, stream>>>(hbf, w1t, Hp);
    k_stat1<<<P_N / 4, 256, 0, stream>>>(Hp, rel, V0, V1, cvec, s1, q1);
    k_y1w<<<P_N, 256, 0, stream>>>(Hp, rel, V0, V1, cvec, s1, q1, g1, be1, Y1);
    k_gemm256<512, false><<<(MROWS / 256) * (1024 / 256), 512, 0, stream>>>(
        Y1, w2t, b2, nullptr, 1024, s2, q2, mkey);
    k_bnfin<<<(P_N * 128) / 256, 256, 0, stream>>>(mkey, s2, q2, g2, be2, out);
}

// Round 17
// 116.350 us; speedup vs baseline: 1.2290x; 1.2290x over previous
//
#include <hip/hip_runtime.h>
#include <hip/hip_bf16.h>
#include <math.h>

#define P_N   2048
#define B_N   10000
#define NB    15
#define MROWS (P_N * NB)   // 30720
#define SPLIT 5
#define BPB   (B_N / SPLIT)  // 2000 boundary points per scan block

typedef __bf16 bf16x8 __attribute__((ext_vector_type(8)));
typedef float  f32x4  __attribute__((ext_vector_type(4)));

__device__ __forceinline__ float bf2f(unsigned short u) {
    union { unsigned int i; float f; } v; v.i = ((unsigned int)u) << 16; return v.f;
}
__device__ __forceinline__ unsigned short f2bf(float f) {
    union { float f; unsigned int i; } v; v.f = f;
    unsigned int i = v.i;
    i += 0x7FFFu + ((i >> 16) & 1u);
    return (unsigned short)(i >> 16);
}
__device__ __forceinline__ void gld_lds16(const unsigned short* g, unsigned short* l) {
    __builtin_amdgcn_global_load_lds(
        (const __attribute__((address_space(1))) unsigned int*)g,
        (__attribute__((address_space(3))) unsigned int*)l, 16, 0, 0);
}
// monotone u32 key for f32 (x<y iff key(x)<key(y)); all real keys > 0
__device__ __forceinline__ unsigned fkey(float f) {
    unsigned b = __float_as_uint(f);
    return (b & 0x80000000u) ? ~b : (b | 0x80000000u);
}
__device__ __forceinline__ float funkey(unsigned key) {
    unsigned b = (key & 0x80000000u) ? (key ^ 0x80000000u) : ~key;
    return __uint_as_float(b);
}

// ---- K0 (fused front): W1/W2 transpose; zero stats+mkey; V/c; h->bf16;
//      boundary scan -> exclusive per-(part,ped,bin) min keys ----------------
// block ranges: [0,144) transpose | [144,2196) zero | [2196,2198) V/c |
//               [2198,2326) hbf | [2326,12566) scan
__global__ __launch_bounds__(256) void k_front(const float* __restrict__ W1,
        const float* __restrict__ W2, unsigned short* __restrict__ w1t,
        unsigned short* __restrict__ w2t, float* __restrict__ stats,
        const float* __restrict__ end_pos, const float* __restrict__ rel_pos,
        const float* __restrict__ bpts, unsigned long long* __restrict__ pkeys,
        const float* __restrict__ h, unsigned short* __restrict__ hbf,
        const float* __restrict__ Wsp, const float* __restrict__ bsp,
        const float* __restrict__ b1, float* __restrict__ V0,
        float* __restrict__ V1, float* __restrict__ cvec) {
    __shared__ unsigned short t[64][65];
    __shared__ unsigned long long s_key[NB];
    int blk = blockIdx.x, tid = threadIdx.x;
    if (blk < 144) {                          // -------- weight transpose
        const float* W; unsigned short* O; int NC, K, tr, tc;
        if (blk < 16) { W = W1; O = w1t; NC = 512; K = 128; tr = blk & 1; tc = blk >> 1; }
        else { int b = blk - 16; W = W2; O = w2t; NC = 1024; K = 512; tr = b & 7; tc = b >> 3; }
        int r0 = tr * 64, c0 = tc * 64;
        int cx = tid & 63, rg = tid >> 6;
#pragma unroll
        for (int i = 0; i < 16; ++i) {
            int r = rg * 16 + i;
            t[r][cx] = f2bf(W[(size_t)(r0 + r) * NC + c0 + cx]);
        }
        __syncthreads();
#pragma unroll
        for (int i = 0; i < 16; ++i) {
            int n = rg * 16 + i;
            O[(size_t)(c0 + n) * K + r0 + cx] = t[cx][n];
        }
    } else if (blk < 2196) {                  // -------- zero stats+mkey (contig)
        int zidx = (blk - 144) * 256 + tid;
        if (zidx < 525056) {                  // (12288 + 8388608) / 16
            uint4 z = {0u, 0u, 0u, 0u};
            ((uint4*)stats)[zidx] = z;
        }
    } else if (blk < 2198) {                  // -------- V = Wsp@W1_top, c
        int col = (blk - 2196) * 256 + tid;   // 0..511
        float v0 = 0.f, v1 = 0.f, cc = 0.f;
        for (int e = 0; e < 64; ++e) {
            float w = W1[(size_t)e * 512 + col];
            v0 = fmaf(Wsp[e], w, v0);
            v1 = fmaf(Wsp[64 + e], w, v1);
            cc = fmaf(bsp[e], w, cc);
        }
        V0[col] = v0; V1[col] = v1; cvec[col] = cc + b1[col];
    } else if (blk < 2326) {                  // -------- h -> bf16 (2048x64)
        int base = (blk - 2198) * 1024 + tid * 4;
        float4 hv = *(const float4*)(h + base);
        unsigned short ub[4] = {f2bf(hv.x), f2bf(hv.y), f2bf(hv.z), f2bf(hv.w)};
        *(uint2*)(hbf + base) = *(uint2*)ub;
    } else {                                  // -------- polar scan (10240 blocks)
        int sb = blk - 2326;
        int p = sb / SPLIT, part = sb % SPLIT;
        if (tid < NB) s_key[tid] = ~0ull;
        __syncthreads();

        float ex = end_pos[2 * p], ey = end_pos[2 * p + 1];
        float rx = rel_pos[2 * p], ry = rel_pos[2 * p + 1];
        float rr = rx * rx + ry * ry;
        float c, s;
        if (rr > 0.0f) { float inv = 1.0f / sqrtf(rr); c = rx * inv; s = ry * inv; }
        else           { c = 1.0f; s = 0.0f; }

        const float T0 = -4.704630109f, T1 = -2.246036774f, T2 = -1.376381920f,
                    T3 = -0.900404044f, T4 = -0.577350269f, T5 = -0.324919696f,
                    T6 = -0.105104235f, T7 =  0.105104235f, T8 =  0.324919696f,
                    T9 =  0.577350269f, T10 = 0.900404044f, T11 = 1.376381920f,
                    T12 = 2.246036774f, T13 = 4.704630109f;

        const float2* bp2 = (const float2*)bpts;
        int bstart = part * BPB;
        for (int b = bstart + tid; b < bstart + BPB; b += 256) {
            float2 pt = bp2[b];
            float dx = pt.x - ex, dy = pt.y - ey;
            float xb = dx * c + dy * s;
            float yb = dy * c - dx * s;
            float r2 = xb * xb + yb * yb;
            bool v3 = yb > T7 * xb;
            float ta = v3 ? T11 : T3;
            bool v2 = yb > ta * xb;
            float tb = v3 ? (v2 ? T13 : T9) : (v2 ? T5 : T1);
            bool v1 = yb > tb * xb;
            float tc = v3 ? (v2 ? (v1 ? 3.0e38f : T12) : (v1 ? T10 : T8))
                          : (v2 ? (v1 ? T6 : T4)       : (v1 ? T2 : T0));
            bool v0 = yb > tc * xb;
            int bin = (v3 ? 8 : 0) + (v2 ? 4 : 0) + (v1 ? 2 : 0) + (v0 ? 1 : 0);
            if (xb > 0.0f) {
                unsigned long long key =
                    ((unsigned long long)__float_as_uint(r2) << 32) | (unsigned int)b;
                atomicMin(&s_key[bin], key);
            }
        }
        __syncthreads();
        if (tid < NB) pkeys[(size_t)part * MROWS + p * NB + tid] = s_key[tid];
    }
}

// ---- K1: reduce parts, choose point/fallback, emit rel + per-ped moments ----
__global__ __launch_bounds__(64) void k_assemble(
        const unsigned long long* __restrict__ pkeys,
        const float* __restrict__ end_pos, const float* __restrict__ rel_pos,
        const float* __restrict__ bpts, float* __restrict__ rel,
        float* __restrict__ pm0, float* __restrict__ pm1, float* __restrict__ pm2,
        float* __restrict__ pm3, float* __restrict__ pm4) {
    int p = blockIdx.x, tid = threadIdx.x;
    float relx = 0.f, rely = 0.f;
    if (tid < NB) {
        float ex = end_pos[2 * p], ey = end_pos[2 * p + 1];
        unsigned long long key = ~0ull;
#pragma unroll
        for (int part = 0; part < SPLIT; ++part) {
            unsigned long long k = pkeys[(size_t)part * MROWS + p * NB + tid];
            key = (k < key) ? k : key;
        }
        float r = sqrtf(__uint_as_float((unsigned int)(key >> 32)));
        if (r <= 2.0f) {
            int b = (int)(key & 0xFFFFFFFFu);
            relx = bpts[2 * b] - ex; rely = bpts[2 * b + 1] - ey;
        } else {
            float rx = rel_pos[2 * p], ry = rel_pos[2 * p + 1];
            float rr = rx * rx + ry * ry;
            float c, s;
            if (rr > 0.0f) { float inv = 1.0f / sqrtf(rr); c = rx * inv; s = ry * inv; }
            else           { c = 1.0f; s = 0.0f; }
            float th = ((float)tid + 0.5f) * (float)(M_PI / 15.0) - (float)(M_PI / 2.0);
            float xc = 2.0f * cosf(th), yc = 2.0f * sinf(th);
            relx = xc * c - yc * s;
            rely = xc * s + yc * c;
        }
        rel[(size_t)(p * NB + tid) * 2]     = relx;
        rel[(size_t)(p * NB + tid) * 2 + 1] = rely;
    }
    // per-ped moments over the 15 cells (lanes >= NB contribute zeros)
    float m0 = relx, m1 = rely, m2 = relx * relx, m3 = relx * rely, m4 = rely * rely;
#pragma unroll
    for (int d = 32; d >= 1; d >>= 1) {
        m0 += __shfl_xor(m0, d); m1 += __shfl_xor(m1, d);
        m2 += __shfl_xor(m2, d); m3 += __shfl_xor(m3, d);
        m4 += __shfl_xor(m4, d);
    }
    if (tid == 0) { pm0[p] = m0; pm1[p] = m1; pm2[p] = m2; pm3[p] = m3; pm4[p] = m4; }
}

// ---- K2: H' = hbf @ W1_bot^T (2048 x 512, K=64) + CLOSED-FORM BN1 stats -----
// Per (p,col): A = Hp + c[col]; B1 = Srx*V0 + Sry*V1;
//   sum_cells y  = 15A + B1
//   sum_cells y² = 15A² + 2A·B1 + (V0²Srx2 + 2V0V1Srxy + V1²Sry2)
__global__ __launch_bounds__(512) void k_hgemm(const unsigned short* __restrict__ hbf,
        const unsigned short* __restrict__ w1t, float* __restrict__ Hp,
        const float* __restrict__ V0, const float* __restrict__ V1,
        const float* __restrict__ cvec,
        const float* __restrict__ pm0, const float* __restrict__ pm1,
        const float* __restrict__ pm2, const float* __restrict__ pm3,
        const float* __restrict__ pm4,
        float* __restrict__ s1, float* __restrict__ q1) {
    __shared__ __align__(16) unsigned short lds[24576];  // 2 subtiles x (A 4096|B 8192)
    int tid = threadIdx.x;
    int bm = blockIdx.x & 15, bnn = blockIdx.x >> 4;     // 16 x 2 blocks
    int row0 = bm << 7, col0 = bnn << 8;
    int lane = tid & 63, wave = tid >> 6;
    int wr = wave >> 2, wc = wave & 3;                   // wave out: 64r x 64c
    int frow = lane & 15, kq = lane >> 4;

    f32x4 zero = {0.f, 0.f, 0.f, 0.f};
    f32x4 acc[4][4];
#pragma unroll
    for (int i = 0; i < 4; ++i)
#pragma unroll
        for (int j = 0; j < 4; ++j) acc[i][j] = zero;

    // 48 chunks (16r x 32k, [kq][frow][8]); wave w stages ch = w*6+k
#pragma unroll
    for (int k = 0; k < 6; ++k) {
        int ch = wave * 6 + k;
        int s = (ch >= 24) ? 1 : 0;
        int r = ch - s * 24;
        unsigned short* dst = lds + s * 12288 + r * 512;
        const unsigned short* src =
            (r < 8) ? (hbf + (size_t)(row0 + r * 16 + frow) * 64 + s * 32 + kq * 8)
                    : (w1t + (size_t)(col0 + (r - 8) * 16 + frow) * 128 + 64 + s * 32 + kq * 8);
        gld_lds16(src, dst);
    }
    asm volatile("s_waitcnt vmcnt(0)" ::: "memory");
    __builtin_amdgcn_s_barrier();
    asm volatile("" ::: "memory");

#pragma unroll
    for (int s = 0; s < 2; ++s) {
        const unsigned short* sub = lds + s * 12288;
        bf16x8 af[4], bfv[4];
#pragma unroll
        for (int i = 0; i < 4; ++i)
            af[i] = *(const bf16x8*)&sub[(wr * 4 + i) * 512 + kq * 128 + frow * 8];
#pragma unroll
        for (int j = 0; j < 4; ++j)
            bfv[j] = *(const bf16x8*)&sub[4096 + (wc * 4 + j) * 512 + kq * 128 + frow * 8];
#pragma unroll
        for (int i = 0; i < 4; ++i)
#pragma unroll
            for (int j = 0; j < 4; ++j)
                acc[i][j] = __builtin_amdgcn_mfma_f32_16x16x32_bf16(af[i], bfv[j], acc[i][j], 0, 0, 0);
    }

    // ---- store Hp + closed-form stats ----
    float v0c[4], v1c[4], cc[4];
#pragma unroll
    for (int j = 0; j < 4; ++j) {
        int col = col0 + wc * 64 + j * 16 + frow;
        v0c[j] = V0[col]; v1c[j] = V1[col]; cc[j] = cvec[col];
    }
    float csum[4] = {0.f, 0.f, 0.f, 0.f}, csq[4] = {0.f, 0.f, 0.f, 0.f};
#pragma unroll
    for (int i = 0; i < 4; ++i) {
#pragma unroll
        for (int r = 0; r < 4; ++r) {
            int row = row0 + wr * 64 + i * 16 + kq * 4 + r;
            float srx = pm0[row], sry = pm1[row];
            float sxx = pm2[row], sxy = pm3[row], syy = pm4[row];
#pragma unroll
            for (int j = 0; j < 4; ++j) {
                int col = col0 + wc * 64 + j * 16 + frow;
                float hp = acc[i][j][r];
                Hp[(size_t)row * 512 + col] = hp;
                float A  = hp + cc[j];
                float B1 = fmaf(srx, v0c[j], sry * v1c[j]);
                float B2 = fmaf(v0c[j] * v0c[j], sxx,
                           fmaf(2.0f * v0c[j] * v1c[j], sxy, v1c[j] * v1c[j] * syy));
                csum[j] += fmaf(15.0f, A, B1);
                csq[j]  += fmaf(15.0f, A * A, fmaf(2.0f * A, B1, B2));
            }
        }
    }
#pragma unroll
    for (int j = 0; j < 4; ++j) {
        int col = col0 + wc * 64 + j * 16 + frow;
        float cs = csum[j], cq = csq[j];
        cs += __shfl_xor(cs, 16); cs += __shfl_xor(cs, 32);
        cq += __shfl_xor(cq, 16); cq += __shfl_xor(cq, 32);
        if (lane < 16) { atomicAdd(&s1[col], cs); atomicAdd(&q1[col], cq); }
    }
}

// ---- K3: write Y1 = relu(sc*y + sh) as bf16 (inline BN1 coefficients) -------
__global__ __launch_bounds__(256) void k_y1w(const float* __restrict__ Hp,
        const float* __restrict__ rel, const float* __restrict__ V0,
        const float* __restrict__ V1, const float* __restrict__ cvec,
        const float* __restrict__ s1, const float* __restrict__ q1,
        const float* __restrict__ g1, const float* __restrict__ be1,
        unsigned short* __restrict__ Y1) {
    int tid = threadIdx.x;
    int p = blockIdx.x;
    int seg = tid & 63, cg = tid >> 6;
    const float invN = 1.0f / (float)MROWS;
    float4 ha = *(const float4*)(Hp + (size_t)p * 512 + seg * 8);
    float4 hb = *(const float4*)(Hp + (size_t)p * 512 + seg * 8 + 4);
    float4 ca = *(const float4*)(cvec + seg * 8);
    float4 cb = *(const float4*)(cvec + seg * 8 + 4);
    float4 va = *(const float4*)(V0 + seg * 8), vb = *(const float4*)(V0 + seg * 8 + 4);
    float4 wa = *(const float4*)(V1 + seg * 8), wb = *(const float4*)(V1 + seg * 8 + 4);
    float hc[8] = {ha.x+ca.x, ha.y+ca.y, ha.z+ca.z, ha.w+ca.w,
                   hb.x+cb.x, hb.y+cb.y, hb.z+cb.z, hb.w+cb.w};
    float v0[8] = {va.x,va.y,va.z,va.w,vb.x,vb.y,vb.z,vb.w};
    float v1[8] = {wa.x,wa.y,wa.z,wa.w,wb.x,wb.y,wb.z,wb.w};
    float sc[8], sh[8];
#pragma unroll
    for (int j = 0; j < 8; ++j) {
        int ccix = seg * 8 + j;
        float m = s1[ccix] * invN;
        float v = q1[ccix] * invN - m * m;
        float k = g1[ccix] * rsqrtf(v + 1e-5f);
        sc[j] = k; sh[j] = be1[ccix] - m * k;
    }
#pragma unroll
    for (int i = 0; i < 4; ++i) {
        int cell = cg + i * 4;
        if (cell < NB) {
            float2 rl = *(const float2*)(rel + (size_t)(p * NB + cell) * 2);
            unsigned short ub[8];
#pragma unroll
            for (int j = 0; j < 8; ++j) {
                float y = fmaf(rl.x, v0[j], fmaf(rl.y, v1[j], hc[j]));
                float z = fmaxf(fmaf(y, sc[j], sh[j]), 0.0f);
                ub[j] = f2bf(z);
            }
            *(uint4*)(Y1 + (size_t)(p * NB + cell) * 512 + seg * 8) = *(uint4*)ub;
        }
    }
}

// ---- GEMM2: 256x256, BK=64, subtile-phase pipeline (R13-verified, ~60 us) ---
template<int K, bool WRITE_C>
__global__ __launch_bounds__(512) void k_gemm256(
        const unsigned short* __restrict__ A, const unsigned short* __restrict__ Bt,
        const float* __restrict__ bias, unsigned short* __restrict__ C,
        int N, float* __restrict__ osum, float* __restrict__ osq,
        unsigned int* __restrict__ mkey) {
    __shared__ __align__(16) unsigned short lds[65536];  // 2 bufs x 32768 elems
    int tid = threadIdx.x;

    int nbt = N >> 8;
    int d = blockIdx.x;
    int m5 = d >> 3;
    int bn = m5 % nbt;
    int bm = (d & 7) + ((m5 / nbt) << 3);
    int row0 = bm << 8, col0 = bn << 8;

    int lane = tid & 63, wave = tid >> 6;
    int wr = wave >> 2, wc = wave & 3;
    int frow = lane & 15, kq = lane >> 4;

    f32x4 zero = {0.f, 0.f, 0.f, 0.f};
    f32x4 acc[8][4];
#pragma unroll
    for (int i = 0; i < 8; ++i)
#pragma unroll
        for (int j = 0; j < 4; ++j) acc[i][j] = zero;

    const unsigned short* gsrc =
        (wave < 4) ? (A  + (size_t)(row0 + (wave << 6) + frow) * K + kq * 8)
                   : (Bt + (size_t)(col0 + ((wave - 4) << 6) + frow) * K + kq * 8);
    unsigned regbase = (wave < 4) ? (unsigned)wave * 2048
                                  : 8192u + (unsigned)(wave - 4) * 2048;

    auto issue2 = [&](int t, int s, int hp) {
        unsigned short* dst = lds + (t & 1) * 32768 + s * 16384 + regbase + hp * 1024;
        const unsigned short* src = gsrc + t * 64 + s * 32 + (size_t)(hp * 32) * K;
        gld_lds16(src,                  dst);
        gld_lds16(src + (size_t)16 * K, dst + 512);
    };

    constexpr int NT = K / 64;
    static_assert(NT >= 2, "need >=2 K-tiles");

    issue2(0, 0, 0); issue2(0, 0, 1); issue2(0, 1, 0); issue2(0, 1, 1);

#pragma unroll
    for (int t = 0; t < NT; ++t) {
        const unsigned short* buf = lds + (t & 1) * 32768;
        bool more = (t + 1 < NT);
#pragma unroll
        for (int s = 0; s < 2; ++s) {
            const unsigned short* sub = buf + s * 16384;
            if (more || s == 0) asm volatile("s_waitcnt vmcnt(4)" ::: "memory");
            else                asm volatile("s_waitcnt vmcnt(0)" ::: "memory");
            __builtin_amdgcn_s_barrier();
            asm volatile("" ::: "memory");
            bf16x8 bfv[4], af[4];
#pragma unroll
            for (int j = 0; j < 4; ++j)
                bfv[j] = *(const bf16x8*)&sub[8192 + (wc * 4 + j) * 512 + kq * 128 + frow * 8];
#pragma unroll
            for (int i = 0; i < 4; ++i)
                af[i] = *(const bf16x8*)&sub[(wr * 8 + i) * 512 + kq * 128 + frow * 8];
            if (more) issue2(t + 1, s, 0);
            __builtin_amdgcn_s_barrier();
            asm volatile("" ::: "memory");
            __builtin_amdgcn_s_setprio(1);
#pragma unroll
            for (int i = 0; i < 4; ++i)
#pragma unroll
                for (int j = 0; j < 4; ++j)
                    acc[i][j] = __builtin_amdgcn_mfma_f32_16x16x32_bf16(af[i], bfv[j], acc[i][j], 0, 0, 0);
            __builtin_amdgcn_s_setprio(0);
#pragma unroll
            for (int i = 0; i < 4; ++i)
                af[i] = *(const bf16x8*)&sub[(wr * 8 + 4 + i) * 512 + kq * 128 + frow * 8];
            if (more) issue2(t + 1, s, 1);
            __builtin_amdgcn_s_barrier();
            asm volatile("" ::: "memory");
            __builtin_amdgcn_s_setprio(1);
#pragma unroll
            for (int i = 0; i < 4; ++i)
#pragma unroll
                for (int j = 0; j < 4; ++j)
                    acc[4 + i][j] = __builtin_amdgcn_mfma_f32_16x16x32_bf16(af[i], bfv[j], acc[4 + i][j], 0, 0, 0);
            __builtin_amdgcn_s_setprio(0);
        }
    }

    float bv[4];
#pragma unroll
    for (int j = 0; j < 4; ++j) bv[j] = bias[col0 + wc * 64 + j * 16 + frow];

#pragma unroll
    for (int j = 0; j < 4; ++j) {
        int col = col0 + wc * 64 + j * 16 + frow;
        float csum = 0.f, csq = 0.f;
#pragma unroll
        for (int i = 0; i < 8; ++i) {
#pragma unroll
            for (int r = 0; r < 4; ++r) {
                float y = acc[i][j][r] + bv[j];
                csum += y; csq = fmaf(y, y, csq);
            }
        }
        csum += __shfl_xor(csum, 16); csum += __shfl_xor(csum, 32);
        csq  += __shfl_xor(csq, 16);  csq  += __shfl_xor(csq, 32);
        if (lane < 16) { atomicAdd(&osum[col], csum); atomicAdd(&osq[col], csq); }
    }

    unsigned short* ldsC = lds;
#pragma unroll
    for (int b = 0; b < 4; ++b) {
        __syncthreads();
        if (wr == (b >> 1)) {
#pragma unroll
            for (int j = 0; j < 4; ++j) {
#pragma unroll
                for (int ii = 0; ii < 4; ++ii) {
                    int i = (b & 1) * 4 + ii;
#pragma unroll
                    for (int r = 0; r < 4; ++r) {
                        float y = acc[i][j][r] + bv[j];
                        ldsC[(ii * 16 + kq * 4 + r) * 264 + wc * 64 + j * 16 + frow] = f2bf(y);
                    }
                }
            }
        }
        __syncthreads();
        if (WRITE_C) {
#pragma unroll
            for (int it = 0; it < 4; ++it) {
                int s = it * 512 + tid;
                int brow = s >> 5, seg = s & 31;
                *(uint4*)(C + (size_t)(row0 + b * 64 + brow) * N + col0 + seg * 8) =
                    *(const uint4*)&ldsC[brow * 264 + seg * 8];
            }
        } else {
            int col = tid & 255, half = tid >> 8;
            int lrow0 = half * 32;
            int grow = row0 + b * 64 + lrow0;
            int curp = grow / 15;
            int rem = 15 - (grow - curp * 15);
            float mx = -3.0e38f;
#pragma unroll
            for (int r = 0; r < 32; ++r) {
                mx = fmaxf(mx, bf2f(ldsC[(lrow0 + r) * 264 + col]));
                if (--rem == 0) {
                    atomicMax(&mkey[(size_t)curp * 1024 + col0 + col], fkey(mx));
                    mx = -3.0e38f; ++curp; rem = 15;
                }
            }
            if (rem != 15)
                atomicMax(&mkey[(size_t)curp * 1024 + col0 + col], fkey(mx));
        }
    }
}

// ---- finalize: out = relu(sc2 * max_y + sh2) from u32-keyed maxima ----------
__global__ void k_bnfin(const unsigned int* __restrict__ mkey, const float* __restrict__ s2,
                        const float* __restrict__ q2, const float* __restrict__ g2,
                        const float* __restrict__ be2, float* __restrict__ out) {
    int idx = blockIdx.x * 256 + threadIdx.x;
    int p = idx >> 7, cb = idx & 127;
    int c0 = cb << 3;
    const float invN = 1.0f / (float)MROWS;
    float4 sa = *(const float4*)(s2 + c0),  sb = *(const float4*)(s2 + c0 + 4);
    float4 qa = *(const float4*)(q2 + c0),  qb = *(const float4*)(q2 + c0 + 4);
    float4 ga = *(const float4*)(g2 + c0),  gb = *(const float4*)(g2 + c0 + 4);
    float4 ea = *(const float4*)(be2 + c0), eb = *(const float4*)(be2 + c0 + 4);
    float sv[8] = {sa.x,sa.y,sa.z,sa.w,sb.x,sb.y,sb.z,sb.w};
    float qv[8] = {qa.x,qa.y,qa.z,qa.w,qb.x,qb.y,qb.z,qb.w};
    float gv[8] = {ga.x,ga.y,ga.z,ga.w,gb.x,gb.y,gb.z,gb.w};
    float ev[8] = {ea.x,ea.y,ea.z,ea.w,eb.x,eb.y,eb.z,eb.w};
    uint4 k0 = *(const uint4*)(mkey + (size_t)p * 1024 + c0);
    uint4 k1 = *(const uint4*)(mkey + (size_t)p * 1024 + c0 + 4);
    unsigned kv[8] = {k0.x,k0.y,k0.z,k0.w,k1.x,k1.y,k1.z,k1.w};
    float o[8];
#pragma unroll
    for (int j = 0; j < 8; ++j) {
        float m = sv[j] * invN;
        float v = qv[j] * invN - m * m;
        float k = gv[j] * rsqrtf(v + 1e-5f);
        float sh = ev[j] - m * k;
        o[j] = fmaxf(fmaf(funkey(kv[j]), k, sh), 0.0f);
    }
    float4 o0 = {o[0], o[1], o[2], o[3]};
    float4 o1 = {o[4], o[5], o[6], o[7]};
    *(float4*)(out + (size_t)p * 1024 + c0)     = o0;
    *(float4*)(out + (size_t)p * 1024 + c0 + 4) = o1;
}

extern "C" void kernel_launch(void* const* d_in, const int* in_sizes, int n_in,
                              void* d_out, int out_size, void* d_ws, size_t ws_size,
                              hipStream_t stream) {
    const float* h       = (const float*)d_in[0];
    const float* end_pos = (const float*)d_in[1];
    const float* rel_pos = (const float*)d_in[2];
    const float* bpts    = (const float*)d_in[3];
    const float* Wsp     = (const float*)d_in[4];
    const float* bsp     = (const float*)d_in[5];
    const float* W1      = (const float*)d_in[6];
    const float* b1      = (const float*)d_in[7];
    const float* g1      = (const float*)d_in[8];
    const float* be1     = (const float*)d_in[9];
    const float* W2      = (const float*)d_in[10];
    const float* b2      = (const float*)d_in[11];
    const float* g2      = (const float*)d_in[12];
    const float* be2     = (const float*)d_in[13];
    float* out = (float*)d_out;

    // ws: [stats 12288][mkey 8388608][pkeys 1228800][w1t 131072][w2t 1048576]
    //     [hbf 262144][V0/V1/c 10240][Hp 4194304][rel 245760][Y1 31457280][pm 40960]
    char* ws = (char*)d_ws;
    float* s1  = (float*)ws;
    float* q1  = s1 + 512;
    float* s2  = q1 + 512;
    float* q2  = s2 + 1024;
    unsigned int* mkey        = (unsigned int*)(ws + 12288);
    unsigned long long* pkeys = (unsigned long long*)(ws + 12288 + 8388608);
    unsigned short* w1t = (unsigned short*)(ws + 9629696);
    unsigned short* w2t = (unsigned short*)(ws + 9760768);
    unsigned short* hbf = (unsigned short*)(ws + 10809344);
    float* V0   = (float*)(ws + 11071488);
    float* V1   = V0 + 512;
    float* cvec = V1 + 512;
    float* Hp   = (float*)(ws + 11081728);
    float* rel  = (float*)(ws + 15276032);
    unsigned short* Y1 = (unsigned short*)(ws + 15521792);
    float* pm0 = (float*)(ws + 46979072);      // 5 x 2048 f32
    float* pm1 = pm0 + 2048;
    float* pm2 = pm1 + 2048;
    float* pm3 = pm2 + 2048;
    float* pm4 = pm3 + 2048;

    k_front<<<12566, 256, 0, stream>>>(W1, W2, w1t, w2t, s1, end_pos, rel_pos,
                                       bpts, pkeys, h, hbf, Wsp, bsp, b1, V0, V1, cvec);
    k_assemble<<<P_N, 64, 0, stream>>>(pkeys, end_pos, rel_pos, bpts, rel,
                                       pm0, pm1, pm2, pm3, pm4);
    k_hgemm<<<32, 512, 0, stream>>>(hbf, w1t, Hp, V0, V1, cvec,
                                    pm0, pm1, pm2, pm3, pm4, s1, q1);
    k_y1w<<<P_N, 256, 0, stream>>>(Hp, rel, V0, V1, cvec, s1, q1, g1, be1, Y1);
    k_gemm256<512, false><<<(MROWS / 256) * (1024 / 256), 512, 0, stream>>>(
        Y1, w2t, b2, nullptr, 1024, s2, q2, mkey);
    k_bnfin<<<(P_N * 128) / 256, 256, 0, stream>>>(mkey, s2, q2, g2, be2, out);
}

// Round 18
// 111.534 us; speedup vs baseline: 1.2821x; 1.0432x over previous
//
#include <hip/hip_runtime.h>
#include <hip/hip_bf16.h>
#include <math.h>

#define P_N   2048
#define B_N   10000
#define NB    15
#define MROWS (P_N * NB)   // 30720
#define SPLIT 5
#define BPB   (B_N / SPLIT)  // 2000 boundary points per scan block

typedef __bf16 bf16x8 __attribute__((ext_vector_type(8)));
typedef float  f32x4  __attribute__((ext_vector_type(4)));

__device__ __forceinline__ float bf2f(unsigned short u) {
    union { unsigned int i; float f; } v; v.i = ((unsigned int)u) << 16; return v.f;
}
__device__ __forceinline__ unsigned short f2bf(float f) {
    union { float f; unsigned int i; } v; v.f = f;
    unsigned int i = v.i;
    i += 0x7FFFu + ((i >> 16) & 1u);
    return (unsigned short)(i >> 16);
}
__device__ __forceinline__ void gld_lds16(const unsigned short* g, unsigned short* l) {
    __builtin_amdgcn_global_load_lds(
        (const __attribute__((address_space(1))) unsigned int*)g,
        (__attribute__((address_space(3))) unsigned int*)l, 16, 0, 0);
}
// monotone u32 key for f32 (x<y iff key(x)<key(y)); all real keys > 0
__device__ __forceinline__ unsigned fkey(float f) {
    unsigned b = __float_as_uint(f);
    return (b & 0x80000000u) ? ~b : (b | 0x80000000u);
}
__device__ __forceinline__ float funkey(unsigned key) {
    unsigned b = (key & 0x80000000u) ? (key ^ 0x80000000u) : ~key;
    return __uint_as_float(b);
}

// ---- K0 (fused front): W1/W2 transpose; zero stats+mkey; V/c; h->bf16;
//      PRUNED boundary scan (4 peds/block) -> exclusive per-(part,ped,bin)
//      min keys. Prune: fallback r=2.0 beats any point with r>2.0, so only
//      r2<=4 points can win; test on unrotated dx^2+dy^2 with +eps margin
//      (rotation norm-preserving +-1ulp); k_assemble's r<=2 test on the
//      stored ROTATED r2 keeps selection exact.
// block ranges: [0,144) transpose | [144,2196) zero | [2196,2198) V/c |
//               [2198,2326) hbf | [2326,4886) scan
__global__ __launch_bounds__(256) void k_front(const float* __restrict__ W1,
        const float* __restrict__ W2, unsigned short* __restrict__ w1t,
        unsigned short* __restrict__ w2t, float* __restrict__ stats,
        const float* __restrict__ end_pos, const float* __restrict__ rel_pos,
        const float* __restrict__ bpts, unsigned long long* __restrict__ pkeys,
        const float* __restrict__ h, unsigned short* __restrict__ hbf,
        const float* __restrict__ Wsp, const float* __restrict__ bsp,
        const float* __restrict__ b1, float* __restrict__ V0,
        float* __restrict__ V1, float* __restrict__ cvec) {
    __shared__ unsigned short t[64][65];
    __shared__ unsigned long long s_key[4][16];
    int blk = blockIdx.x, tid = threadIdx.x;
    if (blk < 144) {                          // -------- weight transpose
        const float* W; unsigned short* O; int NC, K, tr, tc;
        if (blk < 16) { W = W1; O = w1t; NC = 512; K = 128; tr = blk & 1; tc = blk >> 1; }
        else { int b = blk - 16; W = W2; O = w2t; NC = 1024; K = 512; tr = b & 7; tc = b >> 3; }
        int r0 = tr * 64, c0 = tc * 64;
        int cx = tid & 63, rg = tid >> 6;
#pragma unroll
        for (int i = 0; i < 16; ++i) {
            int r = rg * 16 + i;
            t[r][cx] = f2bf(W[(size_t)(r0 + r) * NC + c0 + cx]);
        }
        __syncthreads();
#pragma unroll
        for (int i = 0; i < 16; ++i) {
            int n = rg * 16 + i;
            O[(size_t)(c0 + n) * K + r0 + cx] = t[cx][n];
        }
    } else if (blk < 2196) {                  // -------- zero stats+mkey (contig)
        int zidx = (blk - 144) * 256 + tid;
        if (zidx < 525056) {                  // (12288 + 8388608) / 16
            uint4 z = {0u, 0u, 0u, 0u};
            ((uint4*)stats)[zidx] = z;
        }
    } else if (blk < 2198) {                  // -------- V = Wsp@W1_top, c
        int col = (blk - 2196) * 256 + tid;   // 0..511
        float v0 = 0.f, v1 = 0.f, cc = 0.f;
        for (int e = 0; e < 64; ++e) {
            float w = W1[(size_t)e * 512 + col];
            v0 = fmaf(Wsp[e], w, v0);
            v1 = fmaf(Wsp[64 + e], w, v1);
            cc = fmaf(bsp[e], w, cc);
        }
        V0[col] = v0; V1[col] = v1; cvec[col] = cc + b1[col];
    } else if (blk < 2326) {                  // -------- h -> bf16 (2048x64)
        int base = (blk - 2198) * 1024 + tid * 4;
        float4 hv = *(const float4*)(h + base);
        unsigned short ub[4] = {f2bf(hv.x), f2bf(hv.y), f2bf(hv.z), f2bf(hv.w)};
        *(uint2*)(hbf + base) = *(uint2*)ub;
    } else {                                  // -------- pruned polar scan
        int sb = blk - 2326;                  // 2560 blocks: 512 pgroups x 5 parts
        int pg = sb / SPLIT, part = sb % SPLIT;
        int p0 = pg * 4;
        if (tid < 64) s_key[tid >> 4][tid & 15] = ~0ull;
        __syncthreads();

        float ex[4], ey[4], cr[4], sr[4];
#pragma unroll
        for (int pi = 0; pi < 4; ++pi) {
            ex[pi] = end_pos[2 * (p0 + pi)];
            ey[pi] = end_pos[2 * (p0 + pi) + 1];
            float rx = rel_pos[2 * (p0 + pi)], ry = rel_pos[2 * (p0 + pi) + 1];
            float rr = rx * rx + ry * ry;
            if (rr > 0.0f) { float inv = 1.0f / sqrtf(rr); cr[pi] = rx * inv; sr[pi] = ry * inv; }
            else           { cr[pi] = 1.0f; sr[pi] = 0.0f; }
        }

        const float T0 = -4.704630109f, T1 = -2.246036774f, T2 = -1.376381920f,
                    T3 = -0.900404044f, T4 = -0.577350269f, T5 = -0.324919696f,
                    T6 = -0.105104235f, T7 =  0.105104235f, T8 =  0.324919696f,
                    T9 =  0.577350269f, T10 = 0.900404044f, T11 = 1.376381920f,
                    T12 = 2.246036774f, T13 = 4.704630109f;

        const float2* bp2 = (const float2*)bpts;
        int bstart = part * BPB;
        for (int b = bstart + tid; b < bstart + BPB; b += 256) {
            float2 pt = bp2[b];
#pragma unroll
            for (int pi = 0; pi < 4; ++pi) {
                float dx = pt.x - ex[pi], dy = pt.y - ey[pi];
                float r2u = fmaf(dx, dx, dy * dy);
                if (r2u <= 4.0001f) {            // survivor (~0.2%)
                    float c = cr[pi], s = sr[pi];
                    float xb = dx * c + dy * s;
                    float yb = dy * c - dx * s;
                    if (xb > 0.0f) {
                        float r2 = fmaf(xb, xb, yb * yb);   // rotated (reference) r2
                        bool v3 = yb > T7 * xb;
                        float ta = v3 ? T11 : T3;
                        bool v2 = yb > ta * xb;
                        float tb = v3 ? (v2 ? T13 : T9) : (v2 ? T5 : T1);
                        bool v1 = yb > tb * xb;
                        float tc = v3 ? (v2 ? (v1 ? 3.0e38f : T12) : (v1 ? T10 : T8))
                                      : (v2 ? (v1 ? T6 : T4)       : (v1 ? T2 : T0));
                        bool v0 = yb > tc * xb;
                        int bin = (v3 ? 8 : 0) + (v2 ? 4 : 0) + (v1 ? 2 : 0) + (v0 ? 1 : 0);
                        unsigned long long key =
                            ((unsigned long long)__float_as_uint(r2) << 32) | (unsigned int)b;
                        atomicMin(&s_key[pi][bin], key);
                    }
                }
            }
        }
        __syncthreads();
        if (tid < 64 && (tid & 15) < NB)
            pkeys[(size_t)part * MROWS + (p0 + (tid >> 4)) * NB + (tid & 15)] =
                s_key[tid >> 4][tid & 15];
    }
}

// ---- K1: reduce parts, choose point/fallback, emit rel + per-ped moments ----
__global__ __launch_bounds__(64) void k_assemble(
        const unsigned long long* __restrict__ pkeys,
        const float* __restrict__ end_pos, const float* __restrict__ rel_pos,
        const float* __restrict__ bpts, float* __restrict__ rel,
        float* __restrict__ pm0, float* __restrict__ pm1, float* __restrict__ pm2,
        float* __restrict__ pm3, float* __restrict__ pm4) {
    int p = blockIdx.x, tid = threadIdx.x;
    float relx = 0.f, rely = 0.f;
    if (tid < NB) {
        float ex = end_pos[2 * p], ey = end_pos[2 * p + 1];
        unsigned long long key = ~0ull;
#pragma unroll
        for (int part = 0; part < SPLIT; ++part) {
            unsigned long long k = pkeys[(size_t)part * MROWS + p * NB + tid];
            key = (k < key) ? k : key;
        }
        float r = sqrtf(__uint_as_float((unsigned int)(key >> 32)));
        if (r <= 2.0f) {
            int b = (int)(key & 0xFFFFFFFFu);
            relx = bpts[2 * b] - ex; rely = bpts[2 * b + 1] - ey;
        } else {
            float rx = rel_pos[2 * p], ry = rel_pos[2 * p + 1];
            float rr = rx * rx + ry * ry;
            float c, s;
            if (rr > 0.0f) { float inv = 1.0f / sqrtf(rr); c = rx * inv; s = ry * inv; }
            else           { c = 1.0f; s = 0.0f; }
            float th = ((float)tid + 0.5f) * (float)(M_PI / 15.0) - (float)(M_PI / 2.0);
            float xc = 2.0f * cosf(th), yc = 2.0f * sinf(th);
            relx = xc * c - yc * s;
            rely = xc * s + yc * c;
        }
        rel[(size_t)(p * NB + tid) * 2]     = relx;
        rel[(size_t)(p * NB + tid) * 2 + 1] = rely;
    }
    // per-ped moments over the 15 cells (lanes >= NB contribute zeros)
    float m0 = relx, m1 = rely, m2 = relx * relx, m3 = relx * rely, m4 = rely * rely;
#pragma unroll
    for (int d = 32; d >= 1; d >>= 1) {
        m0 += __shfl_xor(m0, d); m1 += __shfl_xor(m1, d);
        m2 += __shfl_xor(m2, d); m3 += __shfl_xor(m3, d);
        m4 += __shfl_xor(m4, d);
    }
    if (tid == 0) { pm0[p] = m0; pm1[p] = m1; pm2[p] = m2; pm3[p] = m3; pm4[p] = m4; }
}

// ---- K2: H' = hbf @ W1_bot^T (2048 x 512, K=64) + CLOSED-FORM BN1 stats -----
__global__ __launch_bounds__(512) void k_hgemm(const unsigned short* __restrict__ hbf,
        const unsigned short* __restrict__ w1t, float* __restrict__ Hp,
        const float* __restrict__ V0, const float* __restrict__ V1,
        const float* __restrict__ cvec,
        const float* __restrict__ pm0, const float* __restrict__ pm1,
        const float* __restrict__ pm2, const float* __restrict__ pm3,
        const float* __restrict__ pm4,
        float* __restrict__ s1, float* __restrict__ q1) {
    __shared__ __align__(16) unsigned short lds[24576];  // 2 subtiles x (A 4096|B 8192)
    int tid = threadIdx.x;
    int bm = blockIdx.x & 15, bnn = blockIdx.x >> 4;     // 16 x 2 blocks
    int row0 = bm << 7, col0 = bnn << 8;
    int lane = tid & 63, wave = tid >> 6;
    int wr = wave >> 2, wc = wave & 3;                   // wave out: 64r x 64c
    int frow = lane & 15, kq = lane >> 4;

    f32x4 zero = {0.f, 0.f, 0.f, 0.f};
    f32x4 acc[4][4];
#pragma unroll
    for (int i = 0; i < 4; ++i)
#pragma unroll
        for (int j = 0; j < 4; ++j) acc[i][j] = zero;

    // 48 chunks (16r x 32k, [kq][frow][8]); wave w stages ch = w*6+k
#pragma unroll
    for (int k = 0; k < 6; ++k) {
        int ch = wave * 6 + k;
        int s = (ch >= 24) ? 1 : 0;
        int r = ch - s * 24;
        unsigned short* dst = lds + s * 12288 + r * 512;
        const unsigned short* src =
            (r < 8) ? (hbf + (size_t)(row0 + r * 16 + frow) * 64 + s * 32 + kq * 8)
                    : (w1t + (size_t)(col0 + (r - 8) * 16 + frow) * 128 + 64 + s * 32 + kq * 8);
        gld_lds16(src, dst);
    }
    asm volatile("s_waitcnt vmcnt(0)" ::: "memory");
    __builtin_amdgcn_s_barrier();
    asm volatile("" ::: "memory");

#pragma unroll
    for (int s = 0; s < 2; ++s) {
        const unsigned short* sub = lds + s * 12288;
        bf16x8 af[4], bfv[4];
#pragma unroll
        for (int i = 0; i < 4; ++i)
            af[i] = *(const bf16x8*)&sub[(wr * 4 + i) * 512 + kq * 128 + frow * 8];
#pragma unroll
        for (int j = 0; j < 4; ++j)
            bfv[j] = *(const bf16x8*)&sub[4096 + (wc * 4 + j) * 512 + kq * 128 + frow * 8];
#pragma unroll
        for (int i = 0; i < 4; ++i)
#pragma unroll
            for (int j = 0; j < 4; ++j)
                acc[i][j] = __builtin_amdgcn_mfma_f32_16x16x32_bf16(af[i], bfv[j], acc[i][j], 0, 0, 0);
    }

    // ---- store Hp + closed-form stats ----
    float v0c[4], v1c[4], cc[4];
#pragma unroll
    for (int j = 0; j < 4; ++j) {
        int col = col0 + wc * 64 + j * 16 + frow;
        v0c[j] = V0[col]; v1c[j] = V1[col]; cc[j] = cvec[col];
    }
    float csum[4] = {0.f, 0.f, 0.f, 0.f}, csq[4] = {0.f, 0.f, 0.f, 0.f};
#pragma unroll
    for (int i = 0; i < 4; ++i) {
#pragma unroll
        for (int r = 0; r < 4; ++r) {
            int row = row0 + wr * 64 + i * 16 + kq * 4 + r;
            float srx = pm0[row], sry = pm1[row];
            float sxx = pm2[row], sxy = pm3[row], syy = pm4[row];
#pragma unroll
            for (int j = 0; j < 4; ++j) {
                int col = col0 + wc * 64 + j * 16 + frow;
                float hp = acc[i][j][r];
                Hp[(size_t)row * 512 + col] = hp;
                float A  = hp + cc[j];
                float B1 = fmaf(srx, v0c[j], sry * v1c[j]);
                float B2 = fmaf(v0c[j] * v0c[j], sxx,
                           fmaf(2.0f * v0c[j] * v1c[j], sxy, v1c[j] * v1c[j] * syy));
                csum[j] += fmaf(15.0f, A, B1);
                csq[j]  += fmaf(15.0f, A * A, fmaf(2.0f * A, B1, B2));
            }
        }
    }
#pragma unroll
    for (int j = 0; j < 4; ++j) {
        int col = col0 + wc * 64 + j * 16 + frow;
        float cs = csum[j], cq = csq[j];
        cs += __shfl_xor(cs, 16); cs += __shfl_xor(cs, 32);
        cq += __shfl_xor(cq, 16); cq += __shfl_xor(cq, 32);
        if (lane < 16) { atomicAdd(&s1[col], cs); atomicAdd(&q1[col], cq); }
    }
}

// ---- K3: write Y1 = relu(sc*y + sh) as bf16 (inline BN1 coefficients) -------
__global__ __launch_bounds__(256) void k_y1w(const float* __restrict__ Hp,
        const float* __restrict__ rel, const float* __restrict__ V0,
        const float* __restrict__ V1, const float* __restrict__ cvec,
        const float* __restrict__ s1, const float* __restrict__ q1,
        const float* __restrict__ g1, const float* __restrict__ be1,
        unsigned short* __restrict__ Y1) {
    int tid = threadIdx.x;
    int p = blockIdx.x;
    int seg = tid & 63, cg = tid >> 6;
    const float invN = 1.0f / (float)MROWS;
    float4 ha = *(const float4*)(Hp + (size_t)p * 512 + seg * 8);
    float4 hb = *(const float4*)(Hp + (size_t)p * 512 + seg * 8 + 4);
    float4 ca = *(const float4*)(cvec + seg * 8);
    float4 cb = *(const float4*)(cvec + seg * 8 + 4);
    float4 va = *(const float4*)(V0 + seg * 8), vb = *(const float4*)(V0 + seg * 8 + 4);
    float4 wa = *(const float4*)(V1 + seg * 8), wb = *(const float4*)(V1 + seg * 8 + 4);
    float hc[8] = {ha.x+ca.x, ha.y+ca.y, ha.z+ca.z, ha.w+ca.w,
                   hb.x+cb.x, hb.y+cb.y, hb.z+cb.z, hb.w+cb.w};
    float v0[8] = {va.x,va.y,va.z,va.w,vb.x,vb.y,vb.z,vb.w};
    float v1[8] = {wa.x,wa.y,wa.z,wa.w,wb.x,wb.y,wb.z,wb.w};
    float sc[8], sh[8];
#pragma unroll
    for (int j = 0; j < 8; ++j) {
        int ccix = seg * 8 + j;
        float m = s1[ccix] * invN;
        float v = q1[ccix] * invN - m * m;
        float k = g1[ccix] * rsqrtf(v + 1e-5f);
        sc[j] = k; sh[j] = be1[ccix] - m * k;
    }
#pragma unroll
    for (int i = 0; i < 4; ++i) {
        int cell = cg + i * 4;
        if (cell < NB) {
            float2 rl = *(const float2*)(rel + (size_t)(p * NB + cell) * 2);
            unsigned short ub[8];
#pragma unroll
            for (int j = 0; j < 8; ++j) {
                float y = fmaf(rl.x, v0[j], fmaf(rl.y, v1[j], hc[j]));
                float z = fmaxf(fmaf(y, sc[j], sh[j]), 0.0f);
                ub[j] = f2bf(z);
            }
            *(uint4*)(Y1 + (size_t)(p * NB + cell) * 512 + seg * 8) = *(uint4*)ub;
        }
    }
}

// ---- GEMM2: 256x256, BK=64, subtile-phase pipeline (R13-verified, ~60 us) ---
template<int K, bool WRITE_C>
__global__ __launch_bounds__(512) void k_gemm256(
        const unsigned short* __restrict__ A, const unsigned short* __restrict__ Bt,
        const float* __restrict__ bias, unsigned short* __restrict__ C,
        int N, float* __restrict__ osum, float* __restrict__ osq,
        unsigned int* __restrict__ mkey) {
    __shared__ __align__(16) unsigned short lds[65536];  // 2 bufs x 32768 elems
    int tid = threadIdx.x;

    int nbt = N >> 8;
    int d = blockIdx.x;
    int m5 = d >> 3;
    int bn = m5 % nbt;
    int bm = (d & 7) + ((m5 / nbt) << 3);
    int row0 = bm << 8, col0 = bn << 8;

    int lane = tid & 63, wave = tid >> 6;
    int wr = wave >> 2, wc = wave & 3;
    int frow = lane & 15, kq = lane >> 4;

    f32x4 zero = {0.f, 0.f, 0.f, 0.f};
    f32x4 acc[8][4];
#pragma unroll
    for (int i = 0; i < 8; ++i)
#pragma unroll
        for (int j = 0; j < 4; ++j) acc[i][j] = zero;

    const unsigned short* gsrc =
        (wave < 4) ? (A  + (size_t)(row0 + (wave << 6) + frow) * K + kq * 8)
                   : (Bt + (size_t)(col0 + ((wave - 4) << 6) + frow) * K + kq * 8);
    unsigned regbase = (wave < 4) ? (unsigned)wave * 2048
                                  : 8192u + (unsigned)(wave - 4) * 2048;

    auto issue2 = [&](int t, int s, int hp) {
        unsigned short* dst = lds + (t & 1) * 32768 + s * 16384 + regbase + hp * 1024;
        const unsigned short* src = gsrc + t * 64 + s * 32 + (size_t)(hp * 32) * K;
        gld_lds16(src,                  dst);
        gld_lds16(src + (size_t)16 * K, dst + 512);
    };

    constexpr int NT = K / 64;
    static_assert(NT >= 2, "need >=2 K-tiles");

    issue2(0, 0, 0); issue2(0, 0, 1); issue2(0, 1, 0); issue2(0, 1, 1);

#pragma unroll
    for (int t = 0; t < NT; ++t) {
        const unsigned short* buf = lds + (t & 1) * 32768;
        bool more = (t + 1 < NT);
#pragma unroll
        for (int s = 0; s < 2; ++s) {
            const unsigned short* sub = buf + s * 16384;
            if (more || s == 0) asm volatile("s_waitcnt vmcnt(4)" ::: "memory");
            else                asm volatile("s_waitcnt vmcnt(0)" ::: "memory");
            __builtin_amdgcn_s_barrier();
            asm volatile("" ::: "memory");
            bf16x8 bfv[4], af[4];
#pragma unroll
            for (int j = 0; j < 4; ++j)
                bfv[j] = *(const bf16x8*)&sub[8192 + (wc * 4 + j) * 512 + kq * 128 + frow * 8];
#pragma unroll
            for (int i = 0; i < 4; ++i)
                af[i] = *(const bf16x8*)&sub[(wr * 8 + i) * 512 + kq * 128 + frow * 8];
            if (more) issue2(t + 1, s, 0);
            __builtin_amdgcn_s_barrier();
            asm volatile("" ::: "memory");
            __builtin_amdgcn_s_setprio(1);
#pragma unroll
            for (int i = 0; i < 4; ++i)
#pragma unroll
                for (int j = 0; j < 4; ++j)
                    acc[i][j] = __builtin_amdgcn_mfma_f32_16x16x32_bf16(af[i], bfv[j], acc[i][j], 0, 0, 0);
            __builtin_amdgcn_s_setprio(0);
#pragma unroll
            for (int i = 0; i < 4; ++i)
                af[i] = *(const bf16x8*)&sub[(wr * 8 + 4 + i) * 512 + kq * 128 + frow * 8];
            if (more) issue2(t + 1, s, 1);
            __builtin_amdgcn_s_barrier();
            asm volatile("" ::: "memory");
            __builtin_amdgcn_s_setprio(1);
#pragma unroll
            for (int i = 0; i < 4; ++i)
#pragma unroll
                for (int j = 0; j < 4; ++j)
                    acc[4 + i][j] = __builtin_amdgcn_mfma_f32_16x16x32_bf16(af[i], bfv[j], acc[4 + i][j], 0, 0, 0);
            __builtin_amdgcn_s_setprio(0);
        }
    }

    float bv[4];
#pragma unroll
    for (int j = 0; j < 4; ++j) bv[j] = bias[col0 + wc * 64 + j * 16 + frow];

#pragma unroll
    for (int j = 0; j < 4; ++j) {
        int col = col0 + wc * 64 + j * 16 + frow;
        float csum = 0.f, csq = 0.f;
#pragma unroll
        for (int i = 0; i < 8; ++i) {
#pragma unroll
            for (int r = 0; r < 4; ++r) {
                float y = acc[i][j][r] + bv[j];
                csum += y; csq = fmaf(y, y, csq);
            }
        }
        csum += __shfl_xor(csum, 16); csum += __shfl_xor(csum, 32);
        csq  += __shfl_xor(csq, 16);  csq  += __shfl_xor(csq, 32);
        if (lane < 16) { atomicAdd(&osum[col], csum); atomicAdd(&osq[col], csq); }
    }

    unsigned short* ldsC = lds;
#pragma unroll
    for (int b = 0; b < 4; ++b) {
        __syncthreads();
        if (wr == (b >> 1)) {
#pragma unroll
            for (int j = 0; j < 4; ++j) {
#pragma unroll
                for (int ii = 0; ii < 4; ++ii) {
                    int i = (b & 1) * 4 + ii;
#pragma unroll
                    for (int r = 0; r < 4; ++r) {
                        float y = acc[i][j][r] + bv[j];
                        ldsC[(ii * 16 + kq * 4 + r) * 264 + wc * 64 + j * 16 + frow] = f2bf(y);
                    }
                }
            }
        }
        __syncthreads();
        if (WRITE_C) {
#pragma unroll
            for (int it = 0; it < 4; ++it) {
                int s = it * 512 + tid;
                int brow = s >> 5, seg = s & 31;
                *(uint4*)(C + (size_t)(row0 + b * 64 + brow) * N + col0 + seg * 8) =
                    *(const uint4*)&ldsC[brow * 264 + seg * 8];
            }
        } else {
            int col = tid & 255, half = tid >> 8;
            int lrow0 = half * 32;
            int grow = row0 + b * 64 + lrow0;
            int curp = grow / 15;
            int rem = 15 - (grow - curp * 15);
            float mx = -3.0e38f;
#pragma unroll
            for (int r = 0; r < 32; ++r) {
                mx = fmaxf(mx, bf2f(ldsC[(lrow0 + r) * 264 + col]));
                if (--rem == 0) {
                    atomicMax(&mkey[(size_t)curp * 1024 + col0 + col], fkey(mx));
                    mx = -3.0e38f; ++curp; rem = 15;
                }
            }
            if (rem != 15)
                atomicMax(&mkey[(size_t)curp * 1024 + col0 + col], fkey(mx));
        }
    }
}

// ---- finalize: out = relu(sc2 * max_y + sh2) from u32-keyed maxima ----------
__global__ void k_bnfin(const unsigned int* __restrict__ mkey, const float* __restrict__ s2,
                        const float* __restrict__ q2, const float* __restrict__ g2,
                        const float* __restrict__ be2, float* __restrict__ out) {
    int idx = blockIdx.x * 256 + threadIdx.x;
    int p = idx >> 7, cb = idx & 127;
    int c0 = cb << 3;
    const float invN = 1.0f / (float)MROWS;
    float4 sa = *(const float4*)(s2 + c0),  sb = *(const float4*)(s2 + c0 + 4);
    float4 qa = *(const float4*)(q2 + c0),  qb = *(const float4*)(q2 + c0 + 4);
    float4 ga = *(const float4*)(g2 + c0),  gb = *(const float4*)(g2 + c0 + 4);
    float4 ea = *(const float4*)(be2 + c0), eb = *(const float4*)(be2 + c0 + 4);
    float sv[8] = {sa.x,sa.y,sa.z,sa.w,sb.x,sb.y,sb.z,sb.w};
    float qv[8] = {qa.x,qa.y,qa.z,qa.w,qb.x,qb.y,qb.z,qb.w};
    float gv[8] = {ga.x,ga.y,ga.z,ga.w,gb.x,gb.y,gb.z,gb.w};
    float ev[8] = {ea.x,ea.y,ea.z,ea.w,eb.x,eb.y,eb.z,eb.w};
    uint4 k0 = *(const uint4*)(mkey + (size_t)p * 1024 + c0);
    uint4 k1 = *(const uint4*)(mkey + (size_t)p * 1024 + c0 + 4);
    unsigned kv[8] = {k0.x,k0.y,k0.z,k0.w,k1.x,k1.y,k1.z,k1.w};
    float o[8];
#pragma unroll
    for (int j = 0; j < 8; ++j) {
        float m = sv[j] * invN;
        float v = qv[j] * invN - m * m;
        float k = gv[j] * rsqrtf(v + 1e-5f);
        float sh = ev[j] - m * k;
        o[j] = fmaxf(fmaf(funkey(kv[j]), k, sh), 0.0f);
    }
    float4 o0 = {o[0], o[1], o[2], o[3]};
    float4 o1 = {o[4], o[5], o[6], o[7]};
    *(float4*)(out + (size_t)p * 1024 + c0)     = o0;
    *(float4*)(out + (size_t)p * 1024 + c0 + 4) = o1;
}

extern "C" void kernel_launch(void* const* d_in, const int* in_sizes, int n_in,
                              void* d_out, int out_size, void* d_ws, size_t ws_size,
                              hipStream_t stream) {
    const float* h       = (const float*)d_in[0];
    const float* end_pos = (const float*)d_in[1];
    const float* rel_pos = (const float*)d_in[2];
    const float* bpts    = (const float*)d_in[3];
    const float* Wsp     = (const float*)d_in[4];
    const float* bsp     = (const float*)d_in[5];
    const float* W1      = (const float*)d_in[6];
    const float* b1      = (const float*)d_in[7];
    const float* g1      = (const float*)d_in[8];
    const float* be1     = (const float*)d_in[9];
    const float* W2      = (const float*)d_in[10];
    const float* b2      = (const float*)d_in[11];
    const float* g2      = (const float*)d_in[12];
    const float* be2     = (const float*)d_in[13];
    float* out = (float*)d_out;

    // ws: [stats 12288][mkey 8388608][pkeys 1228800][w1t 131072][w2t 1048576]
    //     [hbf 262144][V0/V1/c 10240][Hp 4194304][rel 245760][Y1 31457280][pm 40960]
    char* ws = (char*)d_ws;
    float* s1  = (float*)ws;
    float* q1  = s1 + 512;
    float* s2  = q1 + 512;
    float* q2  = s2 + 1024;
    unsigned int* mkey        = (unsigned int*)(ws + 12288);
    unsigned long long* pkeys = (unsigned long long*)(ws + 12288 + 8388608);
    unsigned short* w1t = (unsigned short*)(ws + 9629696);
    unsigned short* w2t = (unsigned short*)(ws + 9760768);
    unsigned short* hbf = (unsigned short*)(ws + 10809344);
    float* V0   = (float*)(ws + 11071488);
    float* V1   = V0 + 512;
    float* cvec = V1 + 512;
    float* Hp   = (float*)(ws + 11081728);
    float* rel  = (float*)(ws + 15276032);
    unsigned short* Y1 = (unsigned short*)(ws + 15521792);
    float* pm0 = (float*)(ws + 46979072);      // 5 x 2048 f32
    float* pm1 = pm0 + 2048;
    float* pm2 = pm1 + 2048;
    float* pm3 = pm2 + 2048;
    float* pm4 = pm3 + 2048;

    k_front<<<4886, 256, 0, stream>>>(W1, W2, w1t, w2t, s1, end_pos, rel_pos,
                                      bpts, pkeys, h, hbf, Wsp, bsp, b1, V0, V1, cvec);
    k_assemble<<<P_N, 64, 0, stream>>>(pkeys, end_pos, rel_pos, bpts, rel,
                                       pm0, pm1, pm2, pm3, pm4);
    k_hgemm<<<32, 512, 0, stream>>>(hbf, w1t, Hp, V0, V1, cvec,
                                    pm0, pm1, pm2, pm3, pm4, s1, q1);
    k_y1w<<<P_N, 256, 0, stream>>>(Hp, rel, V0, V1, cvec, s1, q1, g1, be1, Y1);
    k_gemm256<512, false><<<(MROWS / 256) * (1024 / 256), 512, 0, stream>>>(
        Y1, w2t, b2, nullptr, 1024, s2, q2, mkey);
    k_bnfin<<<(P_N * 128) / 256, 256, 0, stream>>>(mkey, s2, q2, g2, be2, out);
}